// Round 1
// baseline (747.912 us; speedup 1.0000x reference)
//
#include <hip/hip_runtime.h>

// blendv2c: T=730 scan over G*M=8000 independent hydrological sequences,
// then 15-tap gamma-UH routing. Scan is parallelism-capped (8000 threads =
// 125 waves) -> latency/VALU bound. One thread per (g,m); quad shuffles for
// mean over M; software prefetch of next-step weights/forcing.

#define TS 730
#define GC 2000
#define MM 4
#define TG (TS*GC)

__device__ __forceinline__ float fexp(float x){ return __expf(x); }
__device__ __forceinline__ float flog(float x){ return __logf(x); }
__device__ __forceinline__ float frcp(float x){ return __builtin_amdgcn_rcpf(x); }

__device__ __forceinline__ float qsum(float x){
    x += __shfl_xor(x, 1, 64);
    x += __shfl_xor(x, 2, 64);
    return x;
}

__global__ __launch_bounds__(64, 1) void scan_kernel(
    const float* __restrict__ x_phy,   // (T,G,3)
    const float* __restrict__ wts,     // (T,G,36) = (T,G,3,3,M)
    const float* __restrict__ hyb,     // (G,128)
    float* __restrict__ out,           // d_out: [Q | aet | vad | phr], each T*G
    float* __restrict__ qk,            // ws
    float* __restrict__ qb)            // ws
{
    const int tid = blockIdx.x*64 + threadIdx.x;
    const int g = tid >> 2, m = tid & 3;

    const float* hp = hyb + g*128 + m;
    // param(p) = lb + (ub-lb)*sigmoid(hyb[g, p*4+m])
    #define PARAM(i, lo, hi) ((lo) + ((hi)-(lo)) / (1.0f + __expf(-hp[(i)*4])))
    const float beta    = PARAM(1,  0.5f,   3.0f);   // inf_hbv_beta
    const float bexp    = PARAM(2,  0.001f, 3.0f);   // inf_vic_bexp
    const float alpha   = PARAM(3,  0.3f,   1.0f);   // inf_hmets_alpha
    const float x3      = PARAM(5,  20.0f,  300.0f); // bf1_gr4j_x3
    const float plbfc   = PARAM(6,  0.001f, 0.5f);   // bf1_pl_bfc
    const float plbfn   = PARAM(7,  1.0f,   5.0f);   // bf1_pl_bfn
    const float vbmax   = PARAM(8,  0.1f,   50.0f);  // bf1_vic_bfmax
    const float vbfn    = PARAM(9,  1.0f,   5.0f);   // bf1_vic_bfn
    const float maxperc = PARAM(16, 1.0f,   50.0f);  // perc_gawser_maxperc
    const float crise_p = PARAM(17, 0.1f,   50.0f);  // crise_hbv_crise
    const float c_bfmax = PARAM(18, 0.1f,   50.0f);  // bf2_con_bfmax
    const float g4x3    = PARAM(19, 20.0f,  300.0f); // bf2_gr4j_x3
    const float linbfc  = PARAM(20, 1e-4f,  0.1f);   // bf2_lin_bfc
    const float b2vmax  = PARAM(23, 0.1f,   50.0f);  // bf2_vic_bfmax
    const float b2vn    = PARAM(24, 1.0f,   5.0f);   // bf2_vic_bfn
    const float ddf     = PARAM(25, 0.0f,   20.0f);
    const float Tbm     = PARAM(26, -2.0f,  3.0f);
    const float Tbf     = PARAM(27, -5.0f,  2.0f);
    const float cfr     = PARAM(28, 0.0f,   1.0f);
    const float swi     = PARAM(29, 0.05f,  0.4f);
    const float vmax    = PARAM(30, 10.0f,  500.0f); // vadose_max_level
    #undef PARAM

    const float inv_vmax = 1.0f / vmax;       // one-time precise divisions
    const float inv_x3   = 1.0f / x3;
    const float cfr_ddf  = cfr * ddf;
    const float q2c      = plbfc * vmax;

    // state
    float snow0 = 1e-5f, snow1 = 1e-5f, snow2 = 1e-5f;
    float liqw0 = 1e-5f, liqw1 = 1e-5f, liqw2 = 1e-5f;
    float cum0  = 1e-5f, cum1  = 1e-5f, cum2  = 1e-5f;
    float vad = 0.5f * vmax;
    float phr = 1e-5f;

    // preload t=0 forcing + weights
    const float* xp0 = x_phy + g*3;
    const float* wp0 = wts + g*36 + m;
    float p = xp0[0], tt = xp0[1], pe = xp0[2];
    float r0 = wp0[0],  r1 = wp0[4],  r2 = wp0[8];
    float r3 = wp0[12], r4 = wp0[16], r5 = wp0[20];
    float r6 = wp0[24], r7 = wp0[28], r8 = wp0[32];

    for (int t = 0; t < TS; ++t) {
        // ---- prefetch next step (independent of state chain) ----
        const int tn = (t+1 < TS) ? (t+1) : t;
        const float* xn = x_phy + tn*(GC*3)  + g*3;
        const float* wn = wts   + tn*(GC*36) + g*36 + m;
        const float np = xn[0], ntt = xn[1], npe = xn[2];
        const float n0 = wn[0],  n1 = wn[4],  n2 = wn[8];
        const float n3 = wn[12], n4 = wn[16], n5 = wn[20];
        const float n6 = wn[24], n7 = wn[28], n8 = wn[32];

        // ---- softmax blend weights (unnormalized exp + rcp of sum) ----
        const float e0=fexp(r0), e1=fexp(r1), e2=fexp(r2);
        const float e3=fexp(r3), e4=fexp(r4), e5=fexp(r5);
        const float e6=fexp(r6), e7=fexp(r7), e8=fexp(r8);
        const float is1 = frcp(e0+e1+e2);
        const float is2 = frcp(e3+e4+e5);
        const float is3 = frcp(e6+e7+e8);

        // ---- snow (3 layers) ----
        const float rain  = (tt >= 0.0f) ? p : 0.0f;
        const float snowf = (tt <  0.0f) ? p : 0.0f;
        const float meltb = ddf     * fmaxf(tt - Tbm, 0.0f);
        const float refrb = cfr_ddf * fmaxf(Tbf - tt, 0.0f);
        const float fac2  = fminf(1.0f + cum2*0.01f, 2.0f);  // uses old cum2

        float rel0, rel1, rel2;
        {   // layer 0 (fac=1)
            snow0 += snowf;
            const float melt = fminf(meltb, snow0);
            const float refr = fminf(refrb, liqw0);
            snow0 = snow0 - melt + refr;
            liqw0 = liqw0 + melt - refr;
            const float cap = swi*snow0;
            rel0 = fmaxf(liqw0 - cap, 0.0f);
            liqw0 = fminf(liqw0, cap);
            cum0 = (snow0 > 1e-4f) ? cum0 + melt : 0.0f;
        }
        {   // layer 1 (fac=1)
            snow1 += snowf;
            const float melt = fminf(meltb, snow1);
            const float refr = fminf(refrb, liqw1);
            snow1 = snow1 - melt + refr;
            liqw1 = liqw1 + melt - refr;
            const float cap = swi*snow1;
            rel1 = fmaxf(liqw1 - cap, 0.0f);
            liqw1 = fminf(liqw1, cap);
            cum1 = (snow1 > 1e-4f) ? cum1 + melt : 0.0f;
        }
        {   // layer 2 (fac=fac2)
            snow2 += snowf;
            const float melt = fminf(meltb*fac2, snow2);
            const float refr = fminf(refrb, liqw2);
            snow2 = snow2 - melt + refr;
            liqw2 = liqw2 + melt - refr;
            const float cap = swi*snow2;
            rel2 = fmaxf(liqw2 - cap, 0.0f);
            liqw2 = fminf(liqw2, cap);
            cum2 = (snow2 > 1e-4f) ? cum2 + melt : 0.0f;
        }

        const float water = rain + (rel0+rel1+rel2)*(1.0f/3.0f);

        // ---- soil / infiltration ----
        const float sm     = fminf(fmaxf(vad*inv_vmax, 1e-4f), 1.0f - 1e-4f);
        const float one_sm = 1.0f - sm;
        const float lsm    = flog(sm);
        const float l1sm   = flog(one_sm);
        const float i1 = alpha * water * one_sm;
        const float i2 = water * (1.0f - fexp(beta*lsm));
        const float i3 = water * fexp(bexp*l1sm);
        const float infil = (e0*i1 + e1*i2 + e2*i3) * is1;
        float runoff = fmaxf(water - infil, 0.0f);

        // ---- baseflow 1 ----
        const float y   = vad * inv_x3;
        const float y2  = y*y;
        const float b14 = 1.0f + y2*y2;
        const float q1  = vad * (1.0f - rsqrtf(sqrtf(b14)));   // (1+y^4)^(-1/4)
        const float q2  = q2c   * fexp(plbfn*lsm);
        const float q3  = vbmax * fexp(vbfn*lsm);
        const float bf1 = fminf((e3*q1 + e4*q2 + e5*q3) * is2, vad);

        const float perc  = maxperc * sm;
        const float crise = fminf(crise_p * one_sm, phr);
        const float aet   = pe * sm;
        const float vad_new = vad + infil + crise - bf1 - perc - aet;
        const float over  = fmaxf(vad_new - vmax, 0.0f);
        vad = fminf(fmaxf(vad_new, 1e-5f), vmax);
        runoff += over;

        // ---- baseflow 2 / phreatic ----
        const float c1 = fminf(c_bfmax, phr);
        const float c2 = linbfc * phr;
        const float fr = phr * frcp(phr + g4x3);
        const float c3 = b2vmax * fexp(b2vn * flog(fr));
        const float bf2 = fminf((e6*c1 + e7*c2 + e8*c3) * is3, phr);
        phr = fmaxf(phr + perc - crise - bf2, 1e-5f);

        // ---- mean over M (quad reduce) + store ----
        const float s_run = qsum(runoff);
        const float s_qb  = qsum(bf1 + bf2);
        const float s_aet = qsum(aet);
        const float s_vad = qsum(vad);
        const float s_phr = qsum(phr);
        if (m == 0) {
            const int o = t*GC + g;
            qk[o]         = s_run*0.25f;
            qb[o]         = s_qb *0.25f;
            out[TG   + o] = s_aet*0.25f;
            out[2*TG + o] = s_vad*0.25f;
            out[3*TG + o] = s_phr*0.25f;
        }

        // rotate prefetched values in
        p = np; tt = ntt; pe = npe;
        r0=n0; r1=n1; r2=n2; r3=n3; r4=n4; r5=n5; r6=n6; r7=n7; r8=n8;
    }
}

// Gamma unit hydrographs, stored transposed as uh[l*G + g] for coalesced routing.
// gammaln(a) and a*log(th) cancel under normalization.
__global__ __launch_bounds__(64) void uh_kernel(
    const float* __restrict__ hyb, float* __restrict__ uh1, float* __restrict__ uh2)
{
    const int g = blockIdx.x*64 + threadIdx.x;
    if (g >= GC) return;
    const float* hp = hyb + g*128 + 124;
    const float s0 = 1.0f/(1.0f + __expf(-hp[0]));
    const float s1 = 1.0f/(1.0f + __expf(-hp[1]));
    const float s2 = 1.0f/(1.0f + __expf(-hp[2]));
    const float s3 = 1.0f/(1.0f + __expf(-hp[3]));
    const float a1 = 0.3f  + (20.0f-0.3f) *s0;
    const float b1 = 0.01f + (5.0f-0.01f) *s1;
    const float a2 = 0.5f  + (13.0f-0.5f) *s2;
    const float b2 = 0.15f + (1.5f-0.15f) *s3;

    #pragma unroll
    for (int which = 0; which < 2; ++which) {
        const float a  = which ? a2 : a1;
        const float th = which ? b2 : b1;
        float* dst = which ? uh2 : uh1;
        const float aa = fmaxf(a, 0.0f) + 0.1f;
        const float tv_inv = 1.0f / (fmaxf(th, 0.0f) + 0.5f);
        float lw[15]; float mx = -1e30f;
        #pragma unroll
        for (int l = 0; l < 15; ++l) {
            const float tv = (float)l + 0.5f;
            lw[l] = (aa - 1.0f)*__logf(tv) - tv*tv_inv;
            mx = fmaxf(mx, lw[l]);
        }
        float w[15]; float s = 0.0f;
        #pragma unroll
        for (int l = 0; l < 15; ++l) { w[l] = __expf(lw[l]-mx); s += w[l]; }
        const float inv_s = 1.0f/s;
        #pragma unroll
        for (int l = 0; l < 15; ++l) dst[l*GC + g] = w[l]*inv_s;
    }
}

// Q[t,g] = sum_{l=0..14} qk[t-l,g]*uh1[g,l] + qb[t-l,g]*uh2[g,l]
__global__ __launch_bounds__(256) void route_kernel(
    const float* __restrict__ qk, const float* __restrict__ qb,
    const float* __restrict__ uh1, const float* __restrict__ uh2,
    float* __restrict__ Q)
{
    const int tid = blockIdx.x*256 + threadIdx.x;
    if (tid >= TG) return;
    const int t = tid / GC;
    const int g = tid - t*GC;
    float acc = 0.0f;
    if (t >= 14) {
        #pragma unroll
        for (int l = 0; l < 15; ++l) {
            const int o = tid - l*GC;
            acc += qk[o]*uh1[l*GC+g] + qb[o]*uh2[l*GC+g];
        }
    } else {
        for (int l = 0; l <= t; ++l) {
            const int o = tid - l*GC;
            acc += qk[o]*uh1[l*GC+g] + qb[o]*uh2[l*GC+g];
        }
    }
    Q[tid] = acc;
}

extern "C" void kernel_launch(void* const* d_in, const int* in_sizes, int n_in,
                              void* d_out, int out_size, void* d_ws, size_t ws_size,
                              hipStream_t stream)
{
    const float* x_phy = (const float*)d_in[0];
    const float* wts   = (const float*)d_in[1];
    const float* hyb   = (const float*)d_in[2];
    float* out = (float*)d_out;
    float* ws  = (float*)d_ws;
    float* qk  = ws;                 // T*G
    float* qb  = ws + TG;            // T*G
    float* uh1 = ws + 2*TG;          // 15*G
    float* uh2 = ws + 2*TG + 15*GC;  // 15*G

    uh_kernel   <<<(GC+63)/64,   64,  0, stream>>>(hyb, uh1, uh2);
    scan_kernel <<<(GC*MM)/64,   64,  0, stream>>>(x_phy, wts, hyb, out, qk, qb);
    route_kernel<<<(TG+255)/256, 256, 0, stream>>>(qk, qb, uh1, uh2, out);
}

// Round 2
// 665.232 us; speedup vs baseline: 1.1243x; 1.1243x over previous
//
#include <hip/hip_runtime.h>

// blendv2c: T=730 scan over G*M=8000 independent hydrological sequences,
// then 15-tap gamma-UH routing. Scan is parallelism-capped (8000 threads =
// 125 waves, 1 wave/SIMD) -> latency-bound. R2: depth-5 register prefetch
// pipeline (730=5*146, static slot indices) + DPP quad reductions.

#define TS 730
#define GC 2000
#define MM 4
#define TG (TS*GC)
#define PD 5   // prefetch pipeline depth; must divide TS

__device__ __forceinline__ float fexp(float x){ return __expf(x); }
__device__ __forceinline__ float flog(float x){ return __logf(x); }
__device__ __forceinline__ float frcp(float x){ return __builtin_amdgcn_rcpf(x); }

// quad butterfly sum via DPP (VALU-speed, no LDS round-trip)
__device__ __forceinline__ float qsum(float x){
    float y = __int_as_float(__builtin_amdgcn_mov_dpp(__float_as_int(x), 0xB1, 0xF, 0xF, true)); // quad_perm [1,0,3,2]
    x += y;
    y = __int_as_float(__builtin_amdgcn_mov_dpp(__float_as_int(x), 0x4E, 0xF, 0xF, true));       // quad_perm [2,3,0,1]
    return x + y;
}

__global__ __launch_bounds__(64, 1) void scan_kernel(
    const float* __restrict__ x_phy,   // (T,G,3)
    const float* __restrict__ wts,     // (T,G,36) = (T,G,3,3,M)
    const float* __restrict__ hyb,     // (G,128)
    float* __restrict__ out,           // d_out: [Q | aet | vad | phr], each T*G
    float* __restrict__ qk,            // ws
    float* __restrict__ qb)            // ws
{
    const int tid = blockIdx.x*64 + threadIdx.x;
    const int g = tid >> 2, m = tid & 3;

    const float* hp = hyb + g*128 + m;
    #define PARAM(i, lo, hi) ((lo) + ((hi)-(lo)) / (1.0f + __expf(-hp[(i)*4])))
    const float beta    = PARAM(1,  0.5f,   3.0f);
    const float bexp    = PARAM(2,  0.001f, 3.0f);
    const float alpha   = PARAM(3,  0.3f,   1.0f);
    const float x3      = PARAM(5,  20.0f,  300.0f);
    const float plbfc   = PARAM(6,  0.001f, 0.5f);
    const float plbfn   = PARAM(7,  1.0f,   5.0f);
    const float vbmax   = PARAM(8,  0.1f,   50.0f);
    const float vbfn    = PARAM(9,  1.0f,   5.0f);
    const float maxperc = PARAM(16, 1.0f,   50.0f);
    const float crise_p = PARAM(17, 0.1f,   50.0f);
    const float c_bfmax = PARAM(18, 0.1f,   50.0f);
    const float g4x3    = PARAM(19, 20.0f,  300.0f);
    const float linbfc  = PARAM(20, 1e-4f,  0.1f);
    const float b2vmax  = PARAM(23, 0.1f,   50.0f);
    const float b2vn    = PARAM(24, 1.0f,   5.0f);
    const float ddf     = PARAM(25, 0.0f,   20.0f);
    const float Tbm     = PARAM(26, -2.0f,  3.0f);
    const float Tbf     = PARAM(27, -5.0f,  2.0f);
    const float cfr     = PARAM(28, 0.0f,   1.0f);
    const float swi     = PARAM(29, 0.05f,  0.4f);
    const float vmax    = PARAM(30, 10.0f,  500.0f);
    #undef PARAM

    const float inv_vmax = 1.0f / vmax;
    const float inv_x3   = 1.0f / x3;
    const float cfr_ddf  = cfr * ddf;
    const float q2c      = plbfc * vmax;

    // state
    float snow0 = 1e-5f, snow1 = 1e-5f, snow2 = 1e-5f;
    float liqw0 = 1e-5f, liqw1 = 1e-5f, liqw2 = 1e-5f;
    float cum0  = 1e-5f, cum1  = 1e-5f, cum2  = 1e-5f;
    float vad = 0.5f * vmax;
    float phr = 1e-5f;

    // ---- depth-PD register prefetch pipeline ----
    float fp[PD], ft[PD], fe[PD], w_[PD][9];
    #define LOAD_SLOT(k, tn) { \
        const float* xn = x_phy + (tn)*(GC*3)  + g*3; \
        const float* wn = wts   + (tn)*(GC*36) + g*36 + m; \
        fp[k]=xn[0]; ft[k]=xn[1]; fe[k]=xn[2]; \
        w_[k][0]=wn[0];  w_[k][1]=wn[4];  w_[k][2]=wn[8]; \
        w_[k][3]=wn[12]; w_[k][4]=wn[16]; w_[k][5]=wn[20]; \
        w_[k][6]=wn[24]; w_[k][7]=wn[28]; w_[k][8]=wn[32]; }

    #pragma unroll
    for (int k = 0; k < PD; ++k) LOAD_SLOT(k, k);

    for (int tb = 0; tb < TS; tb += PD) {
        #pragma unroll
        for (int k = 0; k < PD; ++k) {
            const int t = tb + k;

            // pull slot k into locals, then immediately refill slot k for t+PD
            const float p  = fp[k], tt = ft[k], pe = fe[k];
            const float r0 = w_[k][0], r1 = w_[k][1], r2 = w_[k][2];
            const float r3 = w_[k][3], r4 = w_[k][4], r5 = w_[k][5];
            const float r6 = w_[k][6], r7 = w_[k][7], r8 = w_[k][8];
            int tn = t + PD; if (tn >= TS) tn = TS - 1;
            LOAD_SLOT(k, tn);

            // ---- softmax blend weights (unnormalized exp + rcp of sum) ----
            const float e0=fexp(r0), e1=fexp(r1), e2=fexp(r2);
            const float e3=fexp(r3), e4=fexp(r4), e5=fexp(r5);
            const float e6=fexp(r6), e7=fexp(r7), e8=fexp(r8);
            const float is1 = frcp(e0+e1+e2);
            const float is2 = frcp(e3+e4+e5);
            const float is3 = frcp(e6+e7+e8);

            // ---- snow (3 layers) ----
            const float rain  = (tt >= 0.0f) ? p : 0.0f;
            const float snowf = (tt <  0.0f) ? p : 0.0f;
            const float meltb = ddf     * fmaxf(tt - Tbm, 0.0f);
            const float refrb = cfr_ddf * fmaxf(Tbf - tt, 0.0f);
            const float fac2  = fminf(1.0f + cum2*0.01f, 2.0f);  // old cum2

            float rel0, rel1, rel2;
            {   // layer 0 (fac=1)
                snow0 += snowf;
                const float melt = fminf(meltb, snow0);
                const float refr = fminf(refrb, liqw0);
                snow0 = snow0 - melt + refr;
                liqw0 = liqw0 + melt - refr;
                const float cap = swi*snow0;
                rel0 = fmaxf(liqw0 - cap, 0.0f);
                liqw0 = fminf(liqw0, cap);
                cum0 = (snow0 > 1e-4f) ? cum0 + melt : 0.0f;
            }
            {   // layer 1 (fac=1)
                snow1 += snowf;
                const float melt = fminf(meltb, snow1);
                const float refr = fminf(refrb, liqw1);
                snow1 = snow1 - melt + refr;
                liqw1 = liqw1 + melt - refr;
                const float cap = swi*snow1;
                rel1 = fmaxf(liqw1 - cap, 0.0f);
                liqw1 = fminf(liqw1, cap);
                cum1 = (snow1 > 1e-4f) ? cum1 + melt : 0.0f;
            }
            {   // layer 2 (fac=fac2)
                snow2 += snowf;
                const float melt = fminf(meltb*fac2, snow2);
                const float refr = fminf(refrb, liqw2);
                snow2 = snow2 - melt + refr;
                liqw2 = liqw2 + melt - refr;
                const float cap = swi*snow2;
                rel2 = fmaxf(liqw2 - cap, 0.0f);
                liqw2 = fminf(liqw2, cap);
                cum2 = (snow2 > 1e-4f) ? cum2 + melt : 0.0f;
            }

            const float water = rain + (rel0+rel1+rel2)*(1.0f/3.0f);

            // ---- soil / infiltration ----
            const float sm     = fminf(fmaxf(vad*inv_vmax, 1e-4f), 1.0f - 1e-4f);
            const float one_sm = 1.0f - sm;
            const float lsm    = flog(sm);
            const float l1sm   = flog(one_sm);
            const float i1 = alpha * water * one_sm;
            const float i2 = water * (1.0f - fexp(beta*lsm));
            const float i3 = water * fexp(bexp*l1sm);
            const float infil = (e0*i1 + e1*i2 + e2*i3) * is1;
            float runoff = fmaxf(water - infil, 0.0f);

            // ---- baseflow 1 ----
            const float y   = vad * inv_x3;
            const float y2  = y*y;
            const float b14 = 1.0f + y2*y2;
            const float q1  = vad * (1.0f - rsqrtf(sqrtf(b14)));   // (1+y^4)^(-1/4)
            const float q2  = q2c   * fexp(plbfn*lsm);
            const float q3  = vbmax * fexp(vbfn*lsm);
            const float bf1 = fminf((e3*q1 + e4*q2 + e5*q3) * is2, vad);

            const float perc  = maxperc * sm;
            const float crise = fminf(crise_p * one_sm, phr);
            const float aet   = pe * sm;
            const float vad_new = vad + infil + crise - bf1 - perc - aet;
            const float over  = fmaxf(vad_new - vmax, 0.0f);
            vad = fminf(fmaxf(vad_new, 1e-5f), vmax);
            runoff += over;

            // ---- baseflow 2 / phreatic ----
            const float c1 = fminf(c_bfmax, phr);
            const float c2 = linbfc * phr;
            const float fr = phr * frcp(phr + g4x3);
            const float c3 = b2vmax * fexp(b2vn * flog(fr));
            const float bf2 = fminf((e6*c1 + e7*c2 + e8*c3) * is3, phr);
            phr = fmaxf(phr + perc - crise - bf2, 1e-5f);

            // ---- mean over M (DPP quad reduce) + store ----
            const float s_run = qsum(runoff);
            const float s_qb  = qsum(bf1 + bf2);
            const float s_aet = qsum(aet);
            const float s_vad = qsum(vad);
            const float s_phr = qsum(phr);
            if (m == 0) {
                const int o = t*GC + g;
                qk[o]         = s_run*0.25f;
                qb[o]         = s_qb *0.25f;
                out[TG   + o] = s_aet*0.25f;
                out[2*TG + o] = s_vad*0.25f;
                out[3*TG + o] = s_phr*0.25f;
            }
        }
    }
    #undef LOAD_SLOT
}

// Gamma unit hydrographs, stored transposed as uh[l*G + g] for coalesced routing.
__global__ __launch_bounds__(64) void uh_kernel(
    const float* __restrict__ hyb, float* __restrict__ uh1, float* __restrict__ uh2)
{
    const int g = blockIdx.x*64 + threadIdx.x;
    if (g >= GC) return;
    const float* hp = hyb + g*128 + 124;
    const float s0 = 1.0f/(1.0f + __expf(-hp[0]));
    const float s1 = 1.0f/(1.0f + __expf(-hp[1]));
    const float s2 = 1.0f/(1.0f + __expf(-hp[2]));
    const float s3 = 1.0f/(1.0f + __expf(-hp[3]));
    const float a1 = 0.3f  + (20.0f-0.3f) *s0;
    const float b1 = 0.01f + (5.0f-0.01f) *s1;
    const float a2 = 0.5f  + (13.0f-0.5f) *s2;
    const float b2 = 0.15f + (1.5f-0.15f) *s3;

    #pragma unroll
    for (int which = 0; which < 2; ++which) {
        const float a  = which ? a2 : a1;
        const float th = which ? b2 : b1;
        float* dst = which ? uh2 : uh1;
        const float aa = fmaxf(a, 0.0f) + 0.1f;
        const float tv_inv = 1.0f / (fmaxf(th, 0.0f) + 0.5f);
        float lw[15]; float mx = -1e30f;
        #pragma unroll
        for (int l = 0; l < 15; ++l) {
            const float tv = (float)l + 0.5f;
            lw[l] = (aa - 1.0f)*__logf(tv) - tv*tv_inv;
            mx = fmaxf(mx, lw[l]);
        }
        float w[15]; float s = 0.0f;
        #pragma unroll
        for (int l = 0; l < 15; ++l) { w[l] = __expf(lw[l]-mx); s += w[l]; }
        const float inv_s = 1.0f/s;
        #pragma unroll
        for (int l = 0; l < 15; ++l) dst[l*GC + g] = w[l]*inv_s;
    }
}

// Q[t,g] = sum_{l=0..14} qk[t-l,g]*uh1[g,l] + qb[t-l,g]*uh2[g,l]
__global__ __launch_bounds__(256) void route_kernel(
    const float* __restrict__ qk, const float* __restrict__ qb,
    const float* __restrict__ uh1, const float* __restrict__ uh2,
    float* __restrict__ Q)
{
    const int tid = blockIdx.x*256 + threadIdx.x;
    if (tid >= TG) return;
    const int t = tid / GC;
    const int g = tid - t*GC;
    float acc = 0.0f;
    if (t >= 14) {
        #pragma unroll
        for (int l = 0; l < 15; ++l) {
            const int o = tid - l*GC;
            acc += qk[o]*uh1[l*GC+g] + qb[o]*uh2[l*GC+g];
        }
    } else {
        for (int l = 0; l <= t; ++l) {
            const int o = tid - l*GC;
            acc += qk[o]*uh1[l*GC+g] + qb[o]*uh2[l*GC+g];
        }
    }
    Q[tid] = acc;
}

extern "C" void kernel_launch(void* const* d_in, const int* in_sizes, int n_in,
                              void* d_out, int out_size, void* d_ws, size_t ws_size,
                              hipStream_t stream)
{
    const float* x_phy = (const float*)d_in[0];
    const float* wts   = (const float*)d_in[1];
    const float* hyb   = (const float*)d_in[2];
    float* out = (float*)d_out;
    float* ws  = (float*)d_ws;
    float* qk  = ws;                 // T*G
    float* qb  = ws + TG;            // T*G
    float* uh1 = ws + 2*TG;          // 15*G
    float* uh2 = ws + 2*TG + 15*GC;  // 15*G

    uh_kernel   <<<(GC+63)/64,   64,  0, stream>>>(hyb, uh1, uh2);
    scan_kernel <<<(GC*MM)/64,   64,  0, stream>>>(x_phy, wts, hyb, out, qk, qb);
    route_kernel<<<(TG+255)/256, 256, 0, stream>>>(qk, qb, uh1, uh2, out);
}

// Round 7
// 659.693 us; speedup vs baseline: 1.1337x; 1.0084x over previous
//
#include <hip/hip_runtime.h>

// blendv2c R5 (resubmit; R6 bench was a broker timeout, kernel untested):
// cooperative 4-lane-per-(g,m) scan. 16 lanes per group g (4 members x 4
// branch-lanes) -> 32000 threads = 500 waves (was 125). Lane q owns
// blend-branch q of each of the 3 mixture groups; branch formulas unified
// to A + B*exp2(C*log2(S)) -> branchless stream. Snow layers 0,1 are
// provably identical -> one lane-parametrized layer. Routing (15-tap
// gamma UH conv) fused via DPP row_shr:1 delay line; route_kernel gone.
// R5 fix: per-member values are REPLICATED across the 4 branch lanes, so
// sum16 = 4*sum_m -> mean over M is sum16/16, not /4 (R3b was 4x too big).

#define TS 730
#define GC 2000
#define TG (TS*GC)
#define PD 5            // prefetch depth; divides TS
#define LOG2E 1.4426950408889634f

__device__ __forceinline__ float frcp (float x){ return __builtin_amdgcn_rcpf(x); }
__device__ __forceinline__ float fexp2(float x){ return __builtin_amdgcn_exp2f(x); } // v_exp_f32
__device__ __forceinline__ float flog2(float x){ return __builtin_amdgcn_logf(x); }  // v_log_f32

// sum over the 4 lanes of a quad (result replicated in all 4)
__device__ __forceinline__ float qsum(float x){
    x += __int_as_float(__builtin_amdgcn_mov_dpp(__float_as_int(x),0xB1,0xF,0xF,true)); // [1,0,3,2]
    x += __int_as_float(__builtin_amdgcn_mov_dpp(__float_as_int(x),0x4E,0xF,0xF,true)); // [2,3,0,1]
    return x;
}
// shift right by one lane within each 16-lane row (lane0 gets 0)
__device__ __forceinline__ float rshr1(float x){
    return __int_as_float(__builtin_amdgcn_mov_dpp(__float_as_int(x),0x111,0xF,0xF,true));
}
// sum over 16-lane row (result replicated)
__device__ __forceinline__ float sum16(float x){
    x = qsum(x);
    x += __shfl_xor(x, 4, 64);
    x += __shfl_xor(x, 8, 64);
    return x;
}

__global__ __launch_bounds__(64, 1) void scan_kernel(
    const float* __restrict__ x_phy,   // (T,G,3)
    const float* __restrict__ wts,     // (T,G,3,3,M)
    const float* __restrict__ hyb,     // (G,128)
    const float* __restrict__ uh1,     // (15,G) transposed
    const float* __restrict__ uh2,     // (15,G)
    float* __restrict__ out)           // [Q | aet | vad | phr], each T*G
{
    const int tid = blockIdx.x*64 + threadIdx.x;
    const int g  = tid >> 4;
    const int jj = tid & 15;     // lane within group g
    const int m  = jj >> 2;      // ensemble member
    const int q  = jj & 3;       // branch lane

    const float* hp = hyb + g*128 + m;
    #define PARAM(i, lo, hi) ((lo) + ((hi)-(lo)) / (1.0f + __expf(-hp[(i)*4])))
    const float beta    = PARAM(1,  0.5f,   3.0f);
    const float bexp    = PARAM(2,  0.001f, 3.0f);
    const float alpha   = PARAM(3,  0.3f,   1.0f);
    const float x3      = PARAM(5,  20.0f,  300.0f);
    const float plbfc   = PARAM(6,  0.001f, 0.5f);
    const float plbfn   = PARAM(7,  1.0f,   5.0f);
    const float vbmax   = PARAM(8,  0.1f,   50.0f);
    const float vbfn    = PARAM(9,  1.0f,   5.0f);
    const float maxperc = PARAM(16, 1.0f,   50.0f);
    const float crise_p = PARAM(17, 0.1f,   50.0f);
    const float c_bfmax = PARAM(18, 0.1f,   50.0f);
    const float g4x3    = PARAM(19, 20.0f,  300.0f);
    const float linbfc  = PARAM(20, 1e-4f,  0.1f);
    const float b2vmax  = PARAM(23, 0.1f,   50.0f);
    const float b2vn    = PARAM(24, 1.0f,   5.0f);
    const float ddf     = PARAM(25, 0.0f,   20.0f);
    const float Tbm     = PARAM(26, -2.0f,  3.0f);
    const float Tbf     = PARAM(27, -5.0f,  2.0f);
    const float cfr     = PARAM(28, 0.0f,   1.0f);
    const float swi     = PARAM(29, 0.05f,  0.4f);
    const float vmax    = PARAM(30, 10.0f,  500.0f);
    #undef PARAM

    const float inv_vmax = 1.0f / vmax;
    const float inv_x3   = 1.0f / x3;
    const float cfr_ddf  = cfr * ddf;
    const float q2c      = plbfc * vmax;

    // ---- per-lane branch constants (lane q owns branch q; lane 3 masked) ----
    #define SELQ(a,b,c,d) ((q==0)?(a):((q==1)?(b):((q==2)?(c):(d))))
    // infiltration: i_q = water*(A1 + B1*exp2(C1*log2(S1))), S1 = (q==1? sm : 1-sm)
    const float A1  = SELQ(0.0f,  1.0f, 0.0f, 0.0f);
    const float B1  = SELQ(alpha,-1.0f, 1.0f, 0.0f);
    const float C1  = SELQ(1.0f,  beta, bexp, 1.0f);
    // baseflow1: q_q = A2 + B2*exp2(C2*log2(S2)); lane0: vad - vad*(1+y^4)^(-1/4)
    const float B2c = SELQ(0.0f,  q2c,  vbmax, 0.0f);
    const float C2  = SELQ(-0.25f,plbfn,vbfn,  1.0f);
    // baseflow2: lane0 min(c_bfmax,phr); lane1 linbfc*phr; lane2 b2vmax*fr^b2vn
    const float C3  = SELQ(1.0f,  1.0f, b2vn,  b2vn);
    const float B3  = SELQ(0.0f,  0.0f, b2vmax,0.0f);
    // snow: lane0 = layer0 (fac=1, weight 2/3); lanes1-3 = layer2 (weight 1/3,0,0)
    const float relw = SELQ(2.0f/3.0f, 1.0f/3.0f, 0.0f, 0.0f);
    const float ffac = SELQ(0.0f, 0.01f, 0.01f, 0.01f);
    const float emask = (q==3) ? -16384.0f : 0.0f;   // kills lane3 softmax exp
    const int   qsel  = (q==3) ? 2 : q;              // lane3 loads dummy branch
    #undef SELQ

    // ---- routing taps (lane jj holds uh[jj]); delay lines ----
    float tap1 = 0.0f, tap2 = 0.0f;
    if (jj < 15) { tap1 = uh1[jj*GC+g]; tap2 = uh2[jj*GC+g]; }
    float Dk = 0.0f, Db = 0.0f;   // t<14 causal zero-pad matches reference

    // ---- state (one snow layer per lane) ----
    float snow = 1e-5f, liqw = 1e-5f, cum = 1e-5f;
    float vad = 0.5f * vmax;
    float phr = 1e-5f;

    // ---- depth-PD register prefetch pipeline (6 loads/iter) ----
    float fp[PD], ft[PD], fe[PD], wa[PD], wb[PD], wc[PD];
    #define LOAD_SLOT(k, tn) { \
        const float* xn = x_phy + (tn)*(GC*3)  + g*3; \
        const float* wn = wts   + (tn)*(GC*36) + g*36 + qsel*4 + m; \
        fp[k]=xn[0]; ft[k]=xn[1]; fe[k]=xn[2]; \
        wa[k]=wn[0]; wb[k]=wn[12]; wc[k]=wn[24]; }

    #pragma unroll
    for (int k = 0; k < PD; ++k) LOAD_SLOT(k, k);

    int o = g;   // out index t*GC + g, advanced by GC per iter
    for (int tb = 0; tb < TS; tb += PD) {
        #pragma unroll
        for (int k = 0; k < PD; ++k) {
            const int t = tb + k;
            const float p  = fp[k], tt = ft[k], pe = fe[k];
            const float r0 = wa[k], r1 = wb[k], r2 = wc[k];
            int tn = t + PD; if (tn >= TS) tn = TS - 1;
            LOAD_SLOT(k, tn);

            // softmax blend weights: lane q holds exp for branch q of all 3 groups
            const float e0 = fexp2(fmaf(r0, LOG2E, emask));
            const float e1 = fexp2(fmaf(r1, LOG2E, emask));
            const float e2 = fexp2(fmaf(r2, LOG2E, emask));
            const float is1 = frcp(qsum(e0));
            const float is2 = frcp(qsum(e1));
            const float is3 = frcp(qsum(e2));

            // baseflow2 branches (need only phr(t) -> off the sm chain, run early)
            const float fr = phr * frcp(phr + g4x3);
            const float E3 = fexp2(C3 * flog2(fr));
            const float cv = (q==0) ? fminf(c_bfmax, phr)
                           : ((q==1) ? linbfc*phr : B3*E3);
            const float bf2 = fminf(qsum(e2*cv)*is3, phr);

            // snow (lane-parametrized single layer; layers 0,1 identical)
            const float rain  = (tt >= 0.0f) ? p : 0.0f;
            const float snowf = (tt <  0.0f) ? p : 0.0f;
            const float meltb = ddf     * fmaxf(tt - Tbm, 0.0f);
            const float refrb = cfr_ddf * fmaxf(Tbf - tt, 0.0f);
            const float fac   = fminf(fmaf(cum, ffac, 1.0f), 2.0f);  // old cum
            snow += snowf;
            const float melt = fminf(meltb*fac, snow);
            const float refr = fminf(refrb, liqw);
            snow = snow - melt + refr;
            liqw = liqw + melt - refr;
            const float cap = swi*snow;
            const float rel = fmaxf(liqw - cap, 0.0f);
            liqw = fminf(liqw, cap);
            cum = (snow > 1e-4f) ? cum + melt : 0.0f;
            const float water = rain + qsum(rel*relw);   // (2*rel0+rel2)/3

            // soil moisture chains (lane-parallel log/exp)
            const float sm     = fminf(fmaxf(vad*inv_vmax, 1e-4f), 1.0f-1e-4f);
            const float one_sm = 1.0f - sm;
            const float S1 = (q==1) ? sm : one_sm;
            const float E1 = fexp2(C1 * flog2(S1));
            const float iv = water * fmaf(B1, E1, A1);
            const float infil = qsum(e0*iv) * is1;

            const float y  = vad*inv_x3;
            const float y2 = y*y;
            const float S2 = (q==0) ? fmaf(y2, y2, 1.0f) : sm;
            const float E2 = fexp2(C2 * flog2(S2));
            const float A2 = (q==0) ?  vad : 0.0f;
            const float B2 = (q==0) ? -vad : B2c;
            const float qv = fmaf(B2, E2, A2);
            const float bf1 = fminf(qsum(e1*qv)*is2, vad);

            float runoff = fmaxf(water - infil, 0.0f);
            const float perc  = maxperc*sm;
            const float crise = fminf(crise_p*one_sm, phr);
            const float aet   = pe*sm;
            const float vad_new = vad + infil + crise - bf1 - perc - aet;
            runoff += fmaxf(vad_new - vmax, 0.0f);
            vad = fminf(fmaxf(vad_new, 1e-5f), vmax);
            phr = fmaxf(phr + perc - crise - bf2, 1e-5f);

            // means over M: per-member values are replicated across the 4
            // branch lanes, so sum16 = 4*sum_m -> mean = sum16/16.
            const float s_run = sum16(runoff)   * 0.0625f;
            const float s_qb  = sum16(bf1+bf2)  * 0.0625f;
            const float s_aet = sum16(aet)      * 0.0625f;
            const float s_vad = sum16(vad)      * 0.0625f;
            const float s_phr = sum16(phr)      * 0.0625f;

            // fused routing: 16-lane delay line, lane jj holds q(t-jj)
            const float shk = rshr1(Dk), shb = rshr1(Db);
            Dk = (jj==0) ? s_run : shk;
            Db = (jj==0) ? s_qb  : shb;
            const float Q = sum16(fmaf(Dk, tap1, Db*tap2));

            if (jj == 0) {
                out[o]        = Q;
                out[TG   + o] = s_aet;
                out[2*TG + o] = s_vad;
                out[3*TG + o] = s_phr;
            }
            o += GC;
        }
    }
    #undef LOAD_SLOT
}

// Gamma unit hydrographs, transposed uh[l*G+g]. gammaln/a*log(th) cancel
// under normalization.
__global__ __launch_bounds__(64) void uh_kernel(
    const float* __restrict__ hyb, float* __restrict__ uh1, float* __restrict__ uh2)
{
    const int g = blockIdx.x*64 + threadIdx.x;
    if (g >= GC) return;
    const float* hp = hyb + g*128 + 124;
    const float s0 = 1.0f/(1.0f + __expf(-hp[0]));
    const float s1 = 1.0f/(1.0f + __expf(-hp[1]));
    const float s2 = 1.0f/(1.0f + __expf(-hp[2]));
    const float s3 = 1.0f/(1.0f + __expf(-hp[3]));
    const float a1 = 0.3f  + (20.0f-0.3f) *s0;
    const float b1 = 0.01f + (5.0f-0.01f) *s1;
    const float a2 = 0.5f  + (13.0f-0.5f) *s2;
    const float b2 = 0.15f + (1.5f-0.15f) *s3;

    #pragma unroll
    for (int which = 0; which < 2; ++which) {
        const float a  = which ? a2 : a1;
        const float th = which ? b2 : b1;
        float* dst = which ? uh2 : uh1;
        const float aa = fmaxf(a, 0.0f) + 0.1f;
        const float tv_inv = 1.0f / (fmaxf(th, 0.0f) + 0.5f);
        float lw[15]; float mx = -1e30f;
        #pragma unroll
        for (int l = 0; l < 15; ++l) {
            const float tv = (float)l + 0.5f;
            lw[l] = (aa - 1.0f)*__logf(tv) - tv*tv_inv;
            mx = fmaxf(mx, lw[l]);
        }
        float w[15]; float s = 0.0f;
        #pragma unroll
        for (int l = 0; l < 15; ++l) { w[l] = __expf(lw[l]-mx); s += w[l]; }
        const float inv_s = 1.0f/s;
        #pragma unroll
        for (int l = 0; l < 15; ++l) dst[l*GC + g] = w[l]*inv_s;
    }
}

extern "C" void kernel_launch(void* const* d_in, const int* in_sizes, int n_in,
                              void* d_out, int out_size, void* d_ws, size_t ws_size,
                              hipStream_t stream)
{
    const float* x_phy = (const float*)d_in[0];
    const float* wts   = (const float*)d_in[1];
    const float* hyb   = (const float*)d_in[2];
    float* out = (float*)d_out;
    float* ws  = (float*)d_ws;
    float* uh1 = ws;             // 15*G
    float* uh2 = ws + 15*GC;     // 15*G

    uh_kernel  <<<(GC+63)/64, 64, 0, stream>>>(hyb, uh1, uh2);
    scan_kernel<<<GC*16/64,   64, 0, stream>>>(x_phy, wts, hyb, uh1, uh2, out);
}